// Round 22
// baseline (61.211 us; speedup 1.0000x reference)
//
#include <hip/hip_runtime.h>

typedef _Float16 f16x8  __attribute__((ext_vector_type(8)));
typedef _Float16 f16x4  __attribute__((ext_vector_type(4)));
typedef __fp16   hf2    __attribute__((ext_vector_type(2)));
typedef float    f32x4  __attribute__((ext_vector_type(4)));
typedef float    f32x16 __attribute__((ext_vector_type(16)));

namespace {
constexpr int kN = 4, kL = 1024, kS = 1024, kH = 16, kE = 64, kD = 64;
constexpr int kRowF = kH * kE;     // 1024 floats: s-row stride of K and V
constexpr int KVB = 64;            // keys per LDS chunk
constexpr int NCH = kS / KVB;      // 16 chunks
constexpr float SCL = 0.125f * 1.44269504088896340736f;  // 1/sqrt(E)*log2(e)
}

__device__ __forceinline__ unsigned pku(float a, float b) {
  union { hf2 h; unsigned u; } u;
  u.h = __builtin_amdgcn_cvt_pkrtz(a, b);
  return u.u;
}
__device__ __forceinline__ f16x4 pk4(float a, float b, float c, float d) {
  union { hf2 h2[2]; f16x4 v; } u;
  u.h2[0] = __builtin_amdgcn_cvt_pkrtz(a, b);
  u.h2[1] = __builtin_amdgcn_cvt_pkrtz(c, d);
  return u.v;
}
// cross-half-wave (lane ^32) max/sum via permlane32_swap (pure VALU)
__device__ __forceinline__ float xmax32(float t) {
  union { float f; unsigned u; } tu; tu.f = t;
  auto P = __builtin_amdgcn_permlane32_swap(tu.u, tu.u, false, false);
  union { unsigned u; float f; } a, b; a.u = P[0]; b.u = P[1];
  return fmaxf(a.f, b.f);
}
__device__ __forceinline__ float xsum32(float t) {
  union { float f; unsigned u; } tu; tu.f = t;
  auto P = __builtin_amdgcn_permlane32_swap(tu.u, tu.u, false, false);
  union { unsigned u; float f; } a, b; a.u = P[0]; b.u = P[1];
  return a.f + b.f;
}

// Detect all-zero mask/key_lengths: F[0] stays 0 iff every element is zero.
__global__ __launch_bounds__(256)
void flag_kernel(const float* __restrict__ M, const float* __restrict__ KLN,
                 unsigned* __restrict__ F)
{
  constexpr size_t nM = (size_t)kL * kS / 4, nK = (size_t)kN * kS / 4;
  unsigned any = 0;
  for (size_t i = (size_t)blockIdx.x * 256 + threadIdx.x; i < nM + nK;
       i += (size_t)gridDim.x * 256) {
    const f32x4 v = (i < nM) ? reinterpret_cast<const f32x4*>(M)[i]
                             : reinterpret_cast<const f32x4*>(KLN)[i - nM];
    #pragma unroll
    for (int r = 0; r < 4; ++r)
      any |= (__float_as_uint(v[r]) << 1);   // <<1 drops sign: -0 counts as 0
  }
  if (__any(any != 0) && (threadIdx.x & 63) == 0) atomicOr(F, 1u);
}

// STRUCTURAL RESIDENCY: one 1024-thread (16-wave) block per CU. A 16-wave
// block REQUIRES 4 waves/SIMD co-resident, so TLP no longer depends on
// 2-block register packing (R18-R21 showed co-residency tracks registers:
// 64-VGPR builds co-reside, 84-VGPR builds don't -- unified VGPR+AGPR just
// over the 128/wave needed for 4 waves/SIMD). launch_bounds(1024,1) forces
// the compiler to fit <=128 total regs/wave (live state ~116: arch ~84 +
// acc 32), and 1 block/CU means LDS is plentiful (merge buffer back to
// single-pass 38912B).
// Per-wave math BYTE-IDENTICAL to R21 (passed, absmax 3.9e-3): 32q/wave
// 32x32 MFMA, in-block S-split (16 waves = 8 q-tiles x 2 key-halves; each
// wave does one 32-key half of each staged 64-key chunk), pair flash-merge
// through LDS. Verified pieces: swapped scores S^T = K.Q^T via mfma_32x32x16
// (C/D col=lane&31=q, row=(r&3)+8*(r>>2)+4*(lane>>5)=s), XOR-swizzled
// conflict-free LDS, T12 cvt_pkrtz+permlane32_swap P-pack, defer-max THR=8,
// named/const-idx hot state (rule #20), 2-deep prefetch, one __syncthreads
// per chunk, mask-skip flag. Staging: waves 0-7 stage K (2 f4/thread),
// waves 8-11 stage V (4 f4/thread, in-reg transpose), waves 12-15 idle.
__global__ __launch_bounds__(1024, 1)
void attn_fwd_kernel(const float* __restrict__ Q, const float* __restrict__ K,
                     const float* __restrict__ V, const float* __restrict__ M,
                     const float* __restrict__ KLN, float* __restrict__ O,
                     const unsigned* __restrict__ F)
{
  // loop: Ks [2][4096] f16 at 0..16KB, Vt [2][4096] f16 at 16..32KB.
  // epilogue reuse: comb 8x32x36 f32 (36864B) at 0 + mlb 8x32x2 f32 at 36864.
  __shared__ __align__(16) char smem[38912];
  _Float16* Ks = reinterpret_cast<_Float16*>(smem);
  _Float16* Vt = reinterpret_cast<_Float16*>(smem + 16384);

  const int tid  = threadIdx.x;
  const int lane = tid & 63;
  const int wave = tid >> 6;      // 0..15
  const int l31  = lane & 31;     // q within tile; also s/d row in frags
  const int hi   = lane >> 5;
  const int qt   = wave >> 1;     // q-tile 0..7
  const int half = wave & 1;      // 32-key half of each chunk
  const bool kRole = (wave < 8);          // K staging (512 threads)
  const bool vRole = (wave >= 8 && wave < 12);  // V staging (256 threads)
  const int srowK = (tid & 511) >> 4;     // 0..31
  const int scolK = tid & 15;
  const int srowV = (tid >> 4) & 15;      // 0..15 (within V group)
  const int scolV = tid & 15;

  const int useMask = F ? (int)F[0] : 1;   // uniform

  // XCD swizzle (256 % 8 == 0 -> bijective)
  const int swz = ((blockIdx.x & 7) << 5) | (blockIdx.x >> 3);
  const int nh = swz >> 2, qb = swz & 3;
  const int h = nh & (kH - 1), n = nh >> 4;
  const int qrow = qb * 256 + qt * 32 + l31;

  const float* Kp = K + ((size_t)n * kS * kH + h) * kE;
  const float* Vp = V + ((size_t)n * kS * kH + h) * kD;
  const float* Lp = KLN + (size_t)n * kS;
  const float* Mp = M + (size_t)qrow * kS;

  // ---- hoisted Q B-frags (pre-scaled): qf[ec], k = 16*ec + 8*hi + j ----
  f16x8 qf[4];
  {
    const float* Qp = Q + ((size_t)((size_t)n * kL + qrow) * kH + h) * kE;
    #pragma unroll
    for (int ec = 0; ec < 4; ++ec) {
      const f32x4 a = *reinterpret_cast<const f32x4*>(Qp + 16*ec + 8*hi);
      const f32x4 b = *reinterpret_cast<const f32x4*>(Qp + 16*ec + 8*hi + 4);
      union { f16x4 h4[2]; f16x8 v; } u;
      u.h4[0] = pk4(a[0]*SCL, a[1]*SCL, a[2]*SCL, a[3]*SCL);
      u.h4[1] = pk4(b[0]*SCL, b[1]*SCL, b[2]*SCL, b[3]*SCL);
      qf[ec] = u.v;
    }
  }

  // ---- per-thread LDS constants (named scalars; verified math) ----
  const int kxor = (l31 & 7) << 1;
  const int d0 = l31, d1 = 32 + l31;
  const int keyv0 = ((4*((d0>>2)&3) + (d0&3)) ^ (d0>>2)) & 15;
  const int keyv1 = ((4*((d1>>2)&3) + (d1&3)) ^ (d1>>2)) & 15;
  const int vrowb0 = d0 * 64, vrowb1 = d1 * 64;
  int hwv[4];
  #pragma unroll
  for (int jd = 0; jd < 4; ++jd)
    hwv[jd] = ((4*(scolV & 3) + jd) ^ scolV) & 15;

  const f32x16 z16 = {0,0,0,0, 0,0,0,0, 0,0,0,0, 0,0,0,0};
  f32x16 a0 = z16, a1 = z16;       // named accumulators (2 d-tiles)
  float mrun = -1e30f, lsum = 0.f;

  // ---- role-split staging ----
  f32x4 sg[4];
  auto load_kv = [&](int sbase) {
    if (kRole) {
      #pragma unroll
      for (int i = 0; i < 2; ++i)
        sg[i] = *reinterpret_cast<const f32x4*>(Kp + (size_t)(sbase + 32*i + srowK) * kRowF + 4*scolK);
    } else if (vRole) {
      #pragma unroll
      for (int js = 0; js < 4; ++js)
        sg[js] = *reinterpret_cast<const f32x4*>(Vp + (size_t)(sbase + 4*srowV + js) * kRowF + 4*scolV);
    }
  };
  auto kv_write = [&](int buf) {
    if (kRole) {
      #pragma unroll
      for (int i = 0; i < 2; ++i) {
        const int s = 32*i + srowK;
        *reinterpret_cast<f16x4*>(&Ks[buf*4096 + s*64 + ((scolK ^ ((s & 7) << 1)) << 2)]) =
            pk4(sg[i][0], sg[i][1], sg[i][2], sg[i][3]);
      }
    } else if (vRole) {
      #pragma unroll
      for (int jd = 0; jd < 4; ++jd) {
        const int d = 4*scolV + jd;
        *reinterpret_cast<f16x4*>(&Vt[buf*4096 + d*64 + ((srowV ^ hwv[jd]) << 2)]) =
            pk4(sg[0][jd], sg[1][jd], sg[2][jd], sg[3][jd]);
      }
    }
  };

  // ---- prologue: chunk 0 staged, chunk 1 in flight ----
  load_kv(0);
  kv_write(0);
  load_kv(KVB);

  for (int c = 0; c < NCH; ++c) {
    const int cur = c & 1;
    const int s0h = c * KVB + half * 32;       // this wave's 32-key half
    __syncthreads();
    if (c + 1 < NCH) kv_write(cur ^ 1);        // chunk c+1 (loaded body c-1)
    if (c + 2 < NCH) load_kv((c + 2) * KVB);   // written top of body c+1

    // ---- QK^T: ONE 32x32 s-tile (this wave's half), 4 MFMAs ----
    f32x16 cc = z16;
    __builtin_amdgcn_s_setprio(1);
    #pragma unroll
    for (int ec = 0; ec < 4; ++ec) {
      const f16x8 kf = *reinterpret_cast<const f16x8*>(
          &Ks[cur*4096 + l31*64 + half*2048 + ((((ec << 2) + (hi << 1)) ^ kxor) << 2)]);
      cc = __builtin_amdgcn_mfma_f32_32x32x16_f16(kf, qf[ec], cc, 0, 0, 0);
    }
    __builtin_amdgcn_s_setprio(0);

    // ---- logits ----
    float x[16];
    if (useMask) {
      #pragma unroll
      for (int m = 0; m < 4; ++m) {
        const f32x4 mv = *reinterpret_cast<const f32x4*>(Mp + s0h + 8*m + 4*hi);
        const f32x4 lv = *reinterpret_cast<const f32x4*>(Lp + s0h + 8*m + 4*hi);
        #pragma unroll
        for (int r = 0; r < 4; ++r)
          x[4*m+r] = fmaf(mv[r] + lv[r], SCL, cc[4*m+r]);
      }
    } else {
      #pragma unroll
      for (int r = 0; r < 16; ++r) x[r] = cc[r];
    }

    // ---- online softmax (32-key half): tree max + permlane max ----
    float mx[8];
    #pragma unroll
    for (int i = 0; i < 8; ++i) mx[i] = fmaxf(x[i], x[i+8]);
    #pragma unroll
    for (int w = 4; w >= 1; w >>= 1)
      #pragma unroll
      for (int i = 0; i < w; ++i) mx[i] = fmaxf(mx[i], mx[i+w]);
    const float tmax = xmax32(mx[0]);

    if (!__all(tmax <= mrun + 8.f)) {          // defer-max THR=8 (log2)
      const float mnew = fmaxf(mrun, tmax);
      const float rs = __builtin_amdgcn_exp2f(mrun - mnew);
      mrun = mnew; lsum *= rs;
      a0 *= rs; a1 *= rs;
    }
    #pragma unroll
    for (int i = 0; i < 16; ++i)
      x[i] = __builtin_amdgcn_exp2f(x[i] - mrun);
    float s8[8];
    #pragma unroll
    for (int i = 0; i < 8; ++i) s8[i] = x[i] + x[i+8];
    #pragma unroll
    for (int w = 4; w >= 1; w >>= 1)
      #pragma unroll
      for (int i = 0; i < w; ++i) s8[i] += s8[i+w];
    lsum += s8[0];                              // cross-lane sum deferred

    // ---- pack P -> 2 PV B-frags via cvt_pk + permlane32_swap ----
    f16x8 pf0, pf1;
    {
      const unsigned k0 = pku(x[0], x[1]);
      const unsigned k1 = pku(x[2], x[3]);
      const unsigned w0 = pku(x[4], x[5]);
      const unsigned w1 = pku(x[6], x[7]);
      auto X = __builtin_amdgcn_permlane32_swap(k0, w0, false, false);
      auto Y = __builtin_amdgcn_permlane32_swap(k1, w1, false, false);
      union { unsigned u[4]; f16x8 v; } pu;
      pu.u[0] = X[0]; pu.u[1] = Y[0]; pu.u[2] = X[1]; pu.u[3] = Y[1];
      pf0 = pu.v;
    }
    {
      const unsigned k0 = pku(x[8],  x[9]);
      const unsigned k1 = pku(x[10], x[11]);
      const unsigned w0 = pku(x[12], x[13]);
      const unsigned w1 = pku(x[14], x[15]);
      auto X = __builtin_amdgcn_permlane32_swap(k0, w0, false, false);
      auto Y = __builtin_amdgcn_permlane32_swap(k1, w1, false, false);
      union { unsigned u[4]; f16x8 v; } pu;
      pu.u[0] = X[0]; pu.u[1] = Y[0]; pu.u[2] = X[1]; pu.u[3] = Y[1];
      pf1 = pu.v;
    }

    // ---- PV: 2 d-tiles x 2 k-chunks (this wave's half), 4 MFMAs ----
    __builtin_amdgcn_s_setprio(1);
    #pragma unroll
    for (int sc = 0; sc < 2; ++sc) {
      const f16x8 pf = (sc == 0) ? pf0 : pf1;
      const int scg = half*2 + sc;
      {
        const int sl = ((scg << 2) + (hi << 1)) ^ keyv0;
        union { f16x4 h4[2]; f16x8 v; } vu;
        vu.h4[0] = *reinterpret_cast<const f16x4*>(&Vt[cur*4096 + vrowb0 + (sl << 2)]);
        vu.h4[1] = *reinterpret_cast<const f16x4*>(&Vt[cur*4096 + vrowb0 + ((sl ^ 1) << 2)]);
        a0 = __builtin_amdgcn_mfma_f32_32x32x16_f16(vu.v, pf, a0, 0, 0, 0);
      }
      {
        const int sl = ((scg << 2) + (hi << 1)) ^ keyv1;
        union { f16x4 h4[2]; f16x8 v; } vu;
        vu.h4[0] = *reinterpret_cast<const f16x4*>(&Vt[cur*4096 + vrowb1 + (sl << 2)]);
        vu.h4[1] = *reinterpret_cast<const f16x4*>(&Vt[cur*4096 + vrowb1 + ((sl ^ 1) << 2)]);
        a1 = __builtin_amdgcn_mfma_f32_32x32x16_f16(vu.v, pf, a1, 0, 0, 0);
      }
    }
    __builtin_amdgcn_s_setprio(0);
  }

  // ---- epilogue: pair flash-merge through LDS (single pass), store ----
  lsum = xsum32(lsum);                   // full per-half lsum on every lane
  __syncthreads();                       // all LDS chunk reads done
  float* comb = reinterpret_cast<float*>(smem);          // 8 x 32q x 36 f32
  float* mlb  = reinterpret_cast<float*>(smem + 36864);  // 8 x 32q x 2 f32

  float* Op = O + (((size_t)n * kL + qrow) * kH + h) * kD;
  const int cbase = qt*1152 + l31*36;

  if (half == 1) {
    #pragma unroll
    for (int m = 0; m < 4; ++m) {
      f32x4 o;
      o[0] = a0[4*m+0]; o[1] = a0[4*m+1]; o[2] = a0[4*m+2]; o[3] = a0[4*m+3];
      *reinterpret_cast<f32x4*>(&comb[cbase + 8*m + 4*hi]) = o;
    }
    if (hi == 0) {
      mlb[qt*64 + l31*2 + 0] = mrun;
      mlb[qt*64 + l31*2 + 1] = lsum;
    }
  }
  __syncthreads();
  float wA = 0.f, wB = 0.f, inv = 0.f;
  if (half == 0) {
    const float mB = mlb[qt*64 + l31*2 + 0];
    const float lB = mlb[qt*64 + l31*2 + 1];
    const float mM = fmaxf(mrun, mB);
    wA = __builtin_amdgcn_exp2f(mrun - mM);
    wB = __builtin_amdgcn_exp2f(mB - mM);
    inv = 1.f / (lsum * wA + lB * wB);
    #pragma unroll
    for (int m = 0; m < 4; ++m) {
      const f32x4 pB = *reinterpret_cast<const f32x4*>(&comb[cbase + 8*m + 4*hi]);
      f32x4 o;
      #pragma unroll
      for (int r = 0; r < 4; ++r)
        o[r] = (a0[4*m+r] * wA + pB[r] * wB) * inv;
      *reinterpret_cast<f32x4*>(Op + 8*m + 4*hi) = o;
    }
  }
  __syncthreads();
  // pass 2: d-tile 1
  if (half == 1) {
    #pragma unroll
    for (int m = 0; m < 4; ++m) {
      f32x4 o;
      o[0] = a1[4*m+0]; o[1] = a1[4*m+1]; o[2] = a1[4*m+2]; o[3] = a1[4*m+3];
      *reinterpret_cast<f32x4*>(&comb[cbase + 8*m + 4*hi]) = o;
    }
  }
  __syncthreads();
  if (half == 0) {
    #pragma unroll
    for (int m = 0; m < 4; ++m) {
      const f32x4 pB = *reinterpret_cast<const f32x4*>(&comb[cbase + 8*m + 4*hi]);
      f32x4 o;
      #pragma unroll
      for (int r = 0; r < 4; ++r)
        o[r] = (a1[4*m+r] * wA + pB[r] * wB) * inv;
      *reinterpret_cast<f32x4*>(Op + 32 + 8*m + 4*hi) = o;
    }
  }
}

extern "C" void kernel_launch(void* const* d_in, const int* in_sizes, int n_in,
                              void* d_out, int out_size, void* d_ws, size_t ws_size,
                              hipStream_t stream) {
  const float* Q   = (const float*)d_in[0];
  const float* K   = (const float*)d_in[1];
  const float* V   = (const float*)d_in[2];
  const float* M   = (const float*)d_in[3];
  const float* KLN = (const float*)d_in[4];
  float* O = (float*)d_out;

  unsigned* F = nullptr;
  if (ws_size >= sizeof(unsigned)) {
    F = (unsigned*)d_ws;
    hipMemsetAsync(F, 0, sizeof(unsigned), stream);
    flag_kernel<<<dim3(1024), dim3(256), 0, stream>>>(M, KLN, F);
  }

  dim3 grid(kN * kH * (kL / 256));  // 256 blocks (256 q-rows each)
  dim3 block(1024);                 // 16 waves: 8 q-tiles x 2 key-halves
  attn_fwd_kernel<<<grid, block, 0, stream>>>(Q, K, V, M, KLN, O, F);
}

// Round 23
// 46.775 us; speedup vs baseline: 1.3086x; 1.3086x over previous
//
#include <hip/hip_runtime.h>

typedef _Float16 f16x8  __attribute__((ext_vector_type(8)));
typedef _Float16 f16x4  __attribute__((ext_vector_type(4)));
typedef __fp16   hf2    __attribute__((ext_vector_type(2)));
typedef float    f32x4  __attribute__((ext_vector_type(4)));
typedef float    f32x16 __attribute__((ext_vector_type(16)));

namespace {
constexpr int kN = 4, kL = 1024, kS = 1024, kH = 16, kE = 64, kD = 64;
constexpr int kRowF = kH * kE;     // 1024 floats: s-row stride of K and V
constexpr int KVB = 64;            // keys per LDS chunk
constexpr int NCH = kS / KVB;      // 16 chunks
constexpr float SCL = 0.125f * 1.44269504088896340736f;  // 1/sqrt(E)*log2(e)
}

__device__ __forceinline__ unsigned pku(float a, float b) {
  union { hf2 h; unsigned u; } u;
  u.h = __builtin_amdgcn_cvt_pkrtz(a, b);
  return u.u;
}
__device__ __forceinline__ f16x4 pk4(float a, float b, float c, float d) {
  union { hf2 h2[2]; f16x4 v; } u;
  u.h2[0] = __builtin_amdgcn_cvt_pkrtz(a, b);
  u.h2[1] = __builtin_amdgcn_cvt_pkrtz(c, d);
  return u.v;
}
// cross-half-wave (lane ^32) max/sum via permlane32_swap (pure VALU)
__device__ __forceinline__ float xmax32(float t) {
  union { float f; unsigned u; } tu; tu.f = t;
  auto P = __builtin_amdgcn_permlane32_swap(tu.u, tu.u, false, false);
  union { unsigned u; float f; } a, b; a.u = P[0]; b.u = P[1];
  return fmaxf(a.f, b.f);
}
__device__ __forceinline__ float xsum32(float t) {
  union { float f; unsigned u; } tu; tu.f = t;
  auto P = __builtin_amdgcn_permlane32_swap(tu.u, tu.u, false, false);
  union { unsigned u; float f; } a, b; a.u = P[0]; b.u = P[1];
  return a.f + b.f;
}

// Detect all-zero mask/key_lengths: F[0] stays 0 iff every element is zero.
__global__ __launch_bounds__(256)
void flag_kernel(const float* __restrict__ M, const float* __restrict__ KLN,
                 unsigned* __restrict__ F)
{
  constexpr size_t nM = (size_t)kL * kS / 4, nK = (size_t)kN * kS / 4;
  unsigned any = 0;
  for (size_t i = (size_t)blockIdx.x * 256 + threadIdx.x; i < nM + nK;
       i += (size_t)gridDim.x * 256) {
    const f32x4 v = (i < nM) ? reinterpret_cast<const f32x4*>(M)[i]
                             : reinterpret_cast<const f32x4*>(KLN)[i - nM];
    #pragma unroll
    for (int r = 0; r < 4; ++r)
      any |= (__float_as_uint(v[r]) << 1);   // <<1 drops sign: -0 counts as 0
  }
  if (__any(any != 0) && (threadIdx.x & 63) == 0) atomicOr(F, 1u);
}

// SESSION-BEST (R16, 47.1us) restored verbatim. 8-wave/512-thread block =
// 256 q of one (n,h); one staged K/V chunk serves all 8 waves; role-split
// reg staging (waves 0-3 K, 4-7 V); per-wave half-decoupled chains: the two
// 32-key halves of each chunk carry INDEPENDENT (m,lsum,acc) online-softmax
// states (two independent QK->SM->PV chains per wave, scheduler-interleaved),
// flash-merged in registers at the epilogue. 32x32x16 MFMA; swapped scores
// S^T = K.Q^T (C/D col=lane&31=q, row=(reg&3)+8*(reg>>2)+4*(lane>>5)=s);
// XOR-swizzled conflict-free LDS; T12 cvt_pkrtz+permlane32_swap P-pack;
// defer-max THR=8; 2-deep prefetch; one __syncthreads per chunk; mask-skip.
// CRITICAL (learned R13-R22): accumulators are NAMED f32x16 values passed as
// individual references -- address-taken ext_vector arrays go to scratch
// (rule #20); launch_bounds(512,1) -- any bound implying >=4 waves/EU pins
// VGPR<=64..128 and forces ~5-20MB/dispatch scratch spill (R14/R19/R22);
// the 32q/wave state (~110 regs) + 2 waves/SIMD no-spill is the measured
// optimum of this structure family (4-wave variants all spill or thin out).
__global__ __launch_bounds__(512, 1)
void attn_fwd_kernel(const float* __restrict__ Q, const float* __restrict__ K,
                     const float* __restrict__ V, const float* __restrict__ M,
                     const float* __restrict__ KLN, float* __restrict__ O,
                     const unsigned* __restrict__ F)
{
  __shared__ _Float16 Ks[2][KVB * 64];
  __shared__ _Float16 Vt[2][kD * 64];

  const int tid  = threadIdx.x;
  const int lane = tid & 63;
  const int wave = tid >> 6;      // 0..7
  const int l31  = lane & 31;     // q within wave-tile; also s/d row in frags
  const int hi   = lane >> 5;
  const bool kRole = (wave < 4);  // staging role (wave-uniform)
  const int srow = (tid >> 4) & 15;
  const int scol = tid & 15;

  const int useMask = F ? (int)F[0] : 1;   // uniform

  // XCD swizzle (256 % 8 == 0 -> bijective)
  const int swz = ((blockIdx.x & 7) << 5) | (blockIdx.x >> 3);
  const int nh = swz >> 2, qb = swz & 3;
  const int h = nh & (kH - 1), n = nh >> 4;
  const int qrow = qb * 256 + wave * 32 + l31;

  const float* Kp = K + ((size_t)n * kS * kH + h) * kE;
  const float* Vp = V + ((size_t)n * kS * kH + h) * kD;
  const float* Lp = KLN + (size_t)n * kS;
  const float* Mp = M + (size_t)qrow * kS;

  // ---- hoisted Q B-frags (pre-scaled): qf[ec], k = 16*ec + 8*hi + j ----
  f16x8 qf[4];
  {
    const float* Qp = Q + ((size_t)((size_t)n * kL + qrow) * kH + h) * kE;
    #pragma unroll
    for (int ec = 0; ec < 4; ++ec) {
      const f32x4 a = *reinterpret_cast<const f32x4*>(Qp + 16*ec + 8*hi);
      const f32x4 b = *reinterpret_cast<const f32x4*>(Qp + 16*ec + 8*hi + 4);
      union { f16x4 h4[2]; f16x8 v; } u;
      u.h4[0] = pk4(a[0]*SCL, a[1]*SCL, a[2]*SCL, a[3]*SCL);
      u.h4[1] = pk4(b[0]*SCL, b[1]*SCL, b[2]*SCL, b[3]*SCL);
      qf[ec] = u.v;
    }
  }

  // ---- per-thread LDS constants (named scalars; verified round-6 math) ----
  const int kxor = (l31 & 7) << 1;
  const int d0 = l31,      d1 = 32 + l31;
  const int keyv0 = ((4*((d0>>2)&3) + (d0&3)) ^ (d0>>2)) & 15;
  const int keyv1 = ((4*((d1>>2)&3) + (d1&3)) ^ (d1>>2)) & 15;
  const int vrowb0 = d0 * 64, vrowb1 = d1 * 64;
  int hwv[4];
  #pragma unroll
  for (int jd = 0; jd < 4; ++jd)
    hwv[jd] = ((4*(scol & 3) + jd) ^ scol) & 15;

  const f32x16 z16 = {0,0,0,0, 0,0,0,0, 0,0,0,0, 0,0,0,0};
  f32x16 aA0 = z16, aA1 = z16, aB0 = z16, aB1 = z16;   // named accumulators
  float mA = -1e30f, lA = 0.f, mB = -1e30f, lB = 0.f;

  // ---- role-split staging: K waves load 4 K-rows, V waves one V quad ----
  f32x4 sg[4];
  auto load_kv = [&](int sbase) {
    if (kRole) {
      #pragma unroll
      for (int i = 0; i < 4; ++i)
        sg[i] = *reinterpret_cast<const f32x4*>(Kp + (size_t)(sbase + 16*i + srow) * kRowF + 4*scol);
    } else {
      #pragma unroll
      for (int js = 0; js < 4; ++js)
        sg[js] = *reinterpret_cast<const f32x4*>(Vp + (size_t)(sbase + 4*srow + js) * kRowF + 4*scol);
    }
  };
  auto kv_write = [&](int buf) {
    if (kRole) {
      #pragma unroll
      for (int i = 0; i < 4; ++i) {
        const int s = 16*i + srow;
        *reinterpret_cast<f16x4*>(&Ks[buf][s*64 + ((scol ^ ((s & 7) << 1)) << 2)]) =
            pk4(sg[i][0], sg[i][1], sg[i][2], sg[i][3]);
      }
    } else {
      #pragma unroll
      for (int jd = 0; jd < 4; ++jd) {
        const int d = 4*scol + jd;
        *reinterpret_cast<f16x4*>(&Vt[buf][d*64 + ((srow ^ hwv[jd]) << 2)]) =
            pk4(sg[0][jd], sg[1][jd], sg[2][jd], sg[3][jd]);
      }
    }
  };

  // one 32-key half: logits -> per-half online softmax -> pack -> PV.
  // Accumulators passed as INDIVIDUAL references (never address-taken).
  auto half_tail = [&](const f32x16& cc, int hf, int s0h, float& mrun,
                       float& lsum, f32x16& a0, f32x16& a1) {
    float x[16];
    if (useMask) {
      #pragma unroll
      for (int m = 0; m < 4; ++m) {
        const f32x4 mv = *reinterpret_cast<const f32x4*>(Mp + s0h + 8*m + 4*hi);
        const f32x4 lv = *reinterpret_cast<const f32x4*>(Lp + s0h + 8*m + 4*hi);
        #pragma unroll
        for (int r = 0; r < 4; ++r)
          x[4*m+r] = fmaf(mv[r] + lv[r], SCL, cc[4*m+r]);
      }
    } else {
      #pragma unroll
      for (int r = 0; r < 16; ++r) x[r] = cc[r];
    }
    float mx[8];
    #pragma unroll
    for (int i = 0; i < 8; ++i) mx[i] = fmaxf(x[i], x[i+8]);
    #pragma unroll
    for (int w = 4; w >= 1; w >>= 1)
      #pragma unroll
      for (int i = 0; i < w; ++i) mx[i] = fmaxf(mx[i], mx[i+w]);
    const float tmax = xmax32(mx[0]);

    if (!__all(tmax <= mrun + 8.f)) {        // defer-max THR=8 (log2)
      const float mnew = fmaxf(mrun, tmax);
      const float rs = __builtin_amdgcn_exp2f(mrun - mnew);
      mrun = mnew; lsum *= rs;
      a0 *= rs; a1 *= rs;
    }
    #pragma unroll
    for (int i = 0; i < 16; ++i)
      x[i] = __builtin_amdgcn_exp2f(x[i] - mrun);
    float s8[8];
    #pragma unroll
    for (int i = 0; i < 8; ++i) s8[i] = x[i] + x[i+8];
    #pragma unroll
    for (int w = 4; w >= 1; w >>= 1)
      #pragma unroll
      for (int i = 0; i < w; ++i) s8[i] += s8[i+w];
    lsum += s8[0];

    // pack P -> 2 PV B-frags via cvt_pk + permlane32_swap (verified)
    f16x8 pf0, pf1;
    {
      const unsigned k0 = pku(x[0], x[1]);
      const unsigned k1 = pku(x[2], x[3]);
      const unsigned w0 = pku(x[4], x[5]);
      const unsigned w1 = pku(x[6], x[7]);
      auto X = __builtin_amdgcn_permlane32_swap(k0, w0, false, false);
      auto Y = __builtin_amdgcn_permlane32_swap(k1, w1, false, false);
      union { unsigned u[4]; f16x8 v; } pu;
      pu.u[0] = X[0]; pu.u[1] = Y[0]; pu.u[2] = X[1]; pu.u[3] = Y[1];
      pf0 = pu.v;
    }
    {
      const unsigned k0 = pku(x[8],  x[9]);
      const unsigned k1 = pku(x[10], x[11]);
      const unsigned w0 = pku(x[12], x[13]);
      const unsigned w1 = pku(x[14], x[15]);
      auto X = __builtin_amdgcn_permlane32_swap(k0, w0, false, false);
      auto Y = __builtin_amdgcn_permlane32_swap(k1, w1, false, false);
      union { unsigned u[4]; f16x8 v; } pu;
      pu.u[0] = X[0]; pu.u[1] = Y[0]; pu.u[2] = X[1]; pu.u[3] = Y[1];
      pf1 = pu.v;
    }
    const int cur = (s0h >> 6) & 1;
    __builtin_amdgcn_s_setprio(1);
    #pragma unroll
    for (int sc = 0; sc < 2; ++sc) {
      const f16x8 pf = (sc == 0) ? pf0 : pf1;
      const int scg = hf*2 + sc;
      {
        const int sl0 = ((scg << 2) + (hi << 1)) ^ keyv0;
        union { f16x4 h4[2]; f16x8 v; } vu;
        vu.h4[0] = *reinterpret_cast<const f16x4*>(&Vt[cur][vrowb0 + (sl0 << 2)]);
        vu.h4[1] = *reinterpret_cast<const f16x4*>(&Vt[cur][vrowb0 + ((sl0 ^ 1) << 2)]);
        a0 = __builtin_amdgcn_mfma_f32_32x32x16_f16(vu.v, pf, a0, 0, 0, 0);
      }
      {
        const int sl1 = ((scg << 2) + (hi << 1)) ^ keyv1;
        union { f16x4 h4[2]; f16x8 v; } vu;
        vu.h4[0] = *reinterpret_cast<const f16x4*>(&Vt[cur][vrowb1 + (sl1 << 2)]);
        vu.h4[1] = *reinterpret_cast<const f16x4*>(&Vt[cur][vrowb1 + ((sl1 ^ 1) << 2)]);
        a1 = __builtin_amdgcn_mfma_f32_32x32x16_f16(vu.v, pf, a1, 0, 0, 0);
      }
    }
    __builtin_amdgcn_s_setprio(0);
  };

  // ---- prologue: chunk 0 staged, chunk 1 in flight ----
  load_kv(0);
  kv_write(0);
  load_kv(KVB);

  for (int c = 0; c < NCH; ++c) {
    const int cur = c & 1;
    const int s0 = c * KVB;
    __syncthreads();
    if (c + 1 < NCH) kv_write(cur ^ 1);        // chunk c+1 (loaded body c-1)
    if (c + 2 < NCH) load_kv((c + 2) * KVB);   // written top of body c+1

    // ---- QK^T for both independent halves ----
    f32x16 ccA = z16, ccB = z16;
    __builtin_amdgcn_s_setprio(1);
    #pragma unroll
    for (int ec = 0; ec < 4; ++ec) {
      const f16x8 kfA = *reinterpret_cast<const f16x8*>(
          &Ks[cur][l31*64 + ((((ec << 2) + (hi << 1)) ^ kxor) << 2)]);
      ccA = __builtin_amdgcn_mfma_f32_32x32x16_f16(kfA, qf[ec], ccA, 0, 0, 0);
    }
    #pragma unroll
    for (int ec = 0; ec < 4; ++ec) {
      const f16x8 kfB = *reinterpret_cast<const f16x8*>(
          &Ks[cur][l31*64 + 2048 + ((((ec << 2) + (hi << 1)) ^ kxor) << 2)]);
      ccB = __builtin_amdgcn_mfma_f32_32x32x16_f16(kfB, qf[ec], ccB, 0, 0, 0);
    }
    __builtin_amdgcn_s_setprio(0);

    // ---- two independent SM->pack->PV chains (scheduler interleaves) ----
    half_tail(ccA, 0, s0,      mA, lA, aA0, aA1);
    half_tail(ccB, 1, s0 + 32, mB, lB, aB0, aB1);
  }

  // ---- epilogue: in-register flash-merge of the two halves, store ----
  lA = xsum32(lA);
  lB = xsum32(lB);
  const float mM = fmaxf(mA, mB);
  const float wA = __builtin_amdgcn_exp2f(mA - mM);
  const float wB = __builtin_amdgcn_exp2f(mB - mM);
  const float inv = 1.f / (lA * wA + lB * wB);
  float* Op = O + (((size_t)n * kL + qrow) * kH + h) * kD;
  #pragma unroll
  for (int m = 0; m < 4; ++m) {
    f32x4 o;
    #pragma unroll
    for (int r = 0; r < 4; ++r)
      o[r] = (aA0[4*m+r] * wA + aB0[4*m+r] * wB) * inv;
    *reinterpret_cast<f32x4*>(Op + 8*m + 4*hi) = o;
  }
  #pragma unroll
  for (int m = 0; m < 4; ++m) {
    f32x4 o;
    #pragma unroll
    for (int r = 0; r < 4; ++r)
      o[r] = (aA1[4*m+r] * wA + aB1[4*m+r] * wB) * inv;
    *reinterpret_cast<f32x4*>(Op + 32 + 8*m + 4*hi) = o;
  }
}

extern "C" void kernel_launch(void* const* d_in, const int* in_sizes, int n_in,
                              void* d_out, int out_size, void* d_ws, size_t ws_size,
                              hipStream_t stream) {
  const float* Q   = (const float*)d_in[0];
  const float* K   = (const float*)d_in[1];
  const float* V   = (const float*)d_in[2];
  const float* M   = (const float*)d_in[3];
  const float* KLN = (const float*)d_in[4];
  float* O = (float*)d_out;

  unsigned* F = nullptr;
  if (ws_size >= sizeof(unsigned)) {
    F = (unsigned*)d_ws;
    hipMemsetAsync(F, 0, sizeof(unsigned), stream);
    flag_kernel<<<dim3(1024), dim3(256), 0, stream>>>(M, KLN, F);
  }

  dim3 grid(kN * kH * (kL / 256));  // 256 blocks (256 q-rows each)
  dim3 block(512);                  // 8 waves, 32 queries each
  attn_fwd_kernel<<<grid, block, 0, stream>>>(Q, K, V, M, KLN, O, F);
}

// Round 24
// 45.931 us; speedup vs baseline: 1.3327x; 1.0184x over previous
//
#include <hip/hip_runtime.h>

typedef _Float16 f16x8  __attribute__((ext_vector_type(8)));
typedef _Float16 f16x4  __attribute__((ext_vector_type(4)));
typedef __fp16   hf2    __attribute__((ext_vector_type(2)));
typedef float    f32x4  __attribute__((ext_vector_type(4)));
typedef float    f32x16 __attribute__((ext_vector_type(16)));

namespace {
constexpr int kN = 4, kL = 1024, kS = 1024, kH = 16, kE = 64, kD = 64;
constexpr int kRowF = kH * kE;     // 1024 floats: s-row stride of K and V
constexpr int KVB = 64;            // keys per LDS chunk
constexpr int NCH = kS / KVB;      // 16 chunks
constexpr float SCL = 0.125f * 1.44269504088896340736f;  // 1/sqrt(E)*log2(e)
}

__device__ __forceinline__ unsigned pku(float a, float b) {
  union { hf2 h; unsigned u; } u;
  u.h = __builtin_amdgcn_cvt_pkrtz(a, b);
  return u.u;
}
__device__ __forceinline__ f16x4 pk4(float a, float b, float c, float d) {
  union { hf2 h2[2]; f16x4 v; } u;
  u.h2[0] = __builtin_amdgcn_cvt_pkrtz(a, b);
  u.h2[1] = __builtin_amdgcn_cvt_pkrtz(c, d);
  return u.v;
}
// cross-half-wave (lane ^32) max/sum via permlane32_swap (pure VALU)
__device__ __forceinline__ float xmax32(float t) {
  union { float f; unsigned u; } tu; tu.f = t;
  auto P = __builtin_amdgcn_permlane32_swap(tu.u, tu.u, false, false);
  union { unsigned u; float f; } a, b; a.u = P[0]; b.u = P[1];
  return fmaxf(a.f, b.f);
}
__device__ __forceinline__ float xsum32(float t) {
  union { float f; unsigned u; } tu; tu.f = t;
  auto P = __builtin_amdgcn_permlane32_swap(tu.u, tu.u, false, false);
  union { unsigned u; float f; } a, b; a.u = P[0]; b.u = P[1];
  return a.f + b.f;
}

// Detect all-zero mask/key_lengths: F[0] stays 0 iff every element is zero.
__global__ __launch_bounds__(256)
void flag_kernel(const float* __restrict__ M, const float* __restrict__ KLN,
                 unsigned* __restrict__ F)
{
  constexpr size_t nM = (size_t)kL * kS / 4, nK = (size_t)kN * kS / 4;
  unsigned any = 0;
  for (size_t i = (size_t)blockIdx.x * 256 + threadIdx.x; i < nM + nK;
       i += (size_t)gridDim.x * 256) {
    const f32x4 v = (i < nM) ? reinterpret_cast<const f32x4*>(M)[i]
                             : reinterpret_cast<const f32x4*>(KLN)[i - nM];
    #pragma unroll
    for (int r = 0; r < 4; ++r)
      any |= (__float_as_uint(v[r]) << 1);   // <<1 drops sign: -0 counts as 0
  }
  if (__any(any != 0) && (threadIdx.x & 63) == 0) atomicOr(F, 1u);
}

// SESSION-BEST (R16/R23, 46.8us) + unroll-2 main loop: `cur = c&1` becomes
// compile-time constant per unrolled copy, letting LDS buffer bases fold
// into immediate offsets instead of per-iteration VALU address recompute
// (measured VALUBusy 30% vs ~10% algorithmic need -- addresses are the
// excess). Unroll 2 (not 16) to stay inside the 32KB L1 I-cache.
// Structure: 8-wave/512-thread block = 256 q of one (n,h); one staged K/V
// chunk serves all 8 waves; role-split reg staging (waves 0-3 K, 4-7 V);
// per-wave half-decoupled chains: the two 32-key halves of each chunk carry
// INDEPENDENT (m,lsum,acc) online-softmax states, flash-merged in registers
// at the epilogue. 32x32x16 MFMA; swapped scores S^T = K.Q^T (C/D
// col=lane&31=q, row=(reg&3)+8*(reg>>2)+4*(lane>>5)=s); XOR-swizzled
// conflict-free LDS; T12 cvt_pkrtz+permlane32_swap P-pack; defer-max THR=8;
// 2-deep prefetch; one __syncthreads per chunk; mask-skip flag.
// CRITICAL (R13-R22): accumulators are NAMED f32x16 values passed as
// individual references (rule #20: address-taken ext_vector arrays go to
// scratch); launch_bounds(512,1) (any bound implying >=4 waves/EU pins
// VGPR<=64..128 and forces scratch spill).
__global__ __launch_bounds__(512, 1)
void attn_fwd_kernel(const float* __restrict__ Q, const float* __restrict__ K,
                     const float* __restrict__ V, const float* __restrict__ M,
                     const float* __restrict__ KLN, float* __restrict__ O,
                     const unsigned* __restrict__ F)
{
  __shared__ _Float16 Ks[2][KVB * 64];
  __shared__ _Float16 Vt[2][kD * 64];

  const int tid  = threadIdx.x;
  const int lane = tid & 63;
  const int wave = tid >> 6;      // 0..7
  const int l31  = lane & 31;     // q within wave-tile; also s/d row in frags
  const int hi   = lane >> 5;
  const bool kRole = (wave < 4);  // staging role (wave-uniform)
  const int srow = (tid >> 4) & 15;
  const int scol = tid & 15;

  const int useMask = F ? (int)F[0] : 1;   // uniform

  // XCD swizzle (256 % 8 == 0 -> bijective)
  const int swz = ((blockIdx.x & 7) << 5) | (blockIdx.x >> 3);
  const int nh = swz >> 2, qb = swz & 3;
  const int h = nh & (kH - 1), n = nh >> 4;
  const int qrow = qb * 256 + wave * 32 + l31;

  const float* Kp = K + ((size_t)n * kS * kH + h) * kE;
  const float* Vp = V + ((size_t)n * kS * kH + h) * kD;
  const float* Lp = KLN + (size_t)n * kS;
  const float* Mp = M + (size_t)qrow * kS;

  // ---- hoisted Q B-frags (pre-scaled): qf[ec], k = 16*ec + 8*hi + j ----
  f16x8 qf[4];
  {
    const float* Qp = Q + ((size_t)((size_t)n * kL + qrow) * kH + h) * kE;
    #pragma unroll
    for (int ec = 0; ec < 4; ++ec) {
      const f32x4 a = *reinterpret_cast<const f32x4*>(Qp + 16*ec + 8*hi);
      const f32x4 b = *reinterpret_cast<const f32x4*>(Qp + 16*ec + 8*hi + 4);
      union { f16x4 h4[2]; f16x8 v; } u;
      u.h4[0] = pk4(a[0]*SCL, a[1]*SCL, a[2]*SCL, a[3]*SCL);
      u.h4[1] = pk4(b[0]*SCL, b[1]*SCL, b[2]*SCL, b[3]*SCL);
      qf[ec] = u.v;
    }
  }

  // ---- per-thread LDS constants (named scalars; verified round-6 math) ----
  const int kxor = (l31 & 7) << 1;
  const int d0 = l31,      d1 = 32 + l31;
  const int keyv0 = ((4*((d0>>2)&3) + (d0&3)) ^ (d0>>2)) & 15;
  const int keyv1 = ((4*((d1>>2)&3) + (d1&3)) ^ (d1>>2)) & 15;
  const int vrowb0 = d0 * 64, vrowb1 = d1 * 64;
  int hwv[4];
  #pragma unroll
  for (int jd = 0; jd < 4; ++jd)
    hwv[jd] = ((4*(scol & 3) + jd) ^ scol) & 15;

  const f32x16 z16 = {0,0,0,0, 0,0,0,0, 0,0,0,0, 0,0,0,0};
  f32x16 aA0 = z16, aA1 = z16, aB0 = z16, aB1 = z16;   // named accumulators
  float mA = -1e30f, lA = 0.f, mB = -1e30f, lB = 0.f;

  // ---- role-split staging: K waves load 4 K-rows, V waves one V quad ----
  f32x4 sg[4];
  auto load_kv = [&](int sbase) {
    if (kRole) {
      #pragma unroll
      for (int i = 0; i < 4; ++i)
        sg[i] = *reinterpret_cast<const f32x4*>(Kp + (size_t)(sbase + 16*i + srow) * kRowF + 4*scol);
    } else {
      #pragma unroll
      for (int js = 0; js < 4; ++js)
        sg[js] = *reinterpret_cast<const f32x4*>(Vp + (size_t)(sbase + 4*srow + js) * kRowF + 4*scol);
    }
  };
  auto kv_write = [&](int buf) {
    if (kRole) {
      #pragma unroll
      for (int i = 0; i < 4; ++i) {
        const int s = 16*i + srow;
        *reinterpret_cast<f16x4*>(&Ks[buf][s*64 + ((scol ^ ((s & 7) << 1)) << 2)]) =
            pk4(sg[i][0], sg[i][1], sg[i][2], sg[i][3]);
      }
    } else {
      #pragma unroll
      for (int jd = 0; jd < 4; ++jd) {
        const int d = 4*scol + jd;
        *reinterpret_cast<f16x4*>(&Vt[buf][d*64 + ((srow ^ hwv[jd]) << 2)]) =
            pk4(sg[0][jd], sg[1][jd], sg[2][jd], sg[3][jd]);
      }
    }
  };

  // one 32-key half: logits -> per-half online softmax -> pack -> PV.
  // Accumulators passed as INDIVIDUAL references (never address-taken).
  auto half_tail = [&](const f32x16& cc, int hf, int s0h, float& mrun,
                       float& lsum, f32x16& a0, f32x16& a1) {
    float x[16];
    if (useMask) {
      #pragma unroll
      for (int m = 0; m < 4; ++m) {
        const f32x4 mv = *reinterpret_cast<const f32x4*>(Mp + s0h + 8*m + 4*hi);
        const f32x4 lv = *reinterpret_cast<const f32x4*>(Lp + s0h + 8*m + 4*hi);
        #pragma unroll
        for (int r = 0; r < 4; ++r)
          x[4*m+r] = fmaf(mv[r] + lv[r], SCL, cc[4*m+r]);
      }
    } else {
      #pragma unroll
      for (int r = 0; r < 16; ++r) x[r] = cc[r];
    }
    float mx[8];
    #pragma unroll
    for (int i = 0; i < 8; ++i) mx[i] = fmaxf(x[i], x[i+8]);
    #pragma unroll
    for (int w = 4; w >= 1; w >>= 1)
      #pragma unroll
      for (int i = 0; i < w; ++i) mx[i] = fmaxf(mx[i], mx[i+w]);
    const float tmax = xmax32(mx[0]);

    if (!__all(tmax <= mrun + 8.f)) {        // defer-max THR=8 (log2)
      const float mnew = fmaxf(mrun, tmax);
      const float rs = __builtin_amdgcn_exp2f(mrun - mnew);
      mrun = mnew; lsum *= rs;
      a0 *= rs; a1 *= rs;
    }
    #pragma unroll
    for (int i = 0; i < 16; ++i)
      x[i] = __builtin_amdgcn_exp2f(x[i] - mrun);
    float s8[8];
    #pragma unroll
    for (int i = 0; i < 8; ++i) s8[i] = x[i] + x[i+8];
    #pragma unroll
    for (int w = 4; w >= 1; w >>= 1)
      #pragma unroll
      for (int i = 0; i < w; ++i) s8[i] += s8[i+w];
    lsum += s8[0];

    // pack P -> 2 PV B-frags via cvt_pk + permlane32_swap (verified)
    f16x8 pf0, pf1;
    {
      const unsigned k0 = pku(x[0], x[1]);
      const unsigned k1 = pku(x[2], x[3]);
      const unsigned w0 = pku(x[4], x[5]);
      const unsigned w1 = pku(x[6], x[7]);
      auto X = __builtin_amdgcn_permlane32_swap(k0, w0, false, false);
      auto Y = __builtin_amdgcn_permlane32_swap(k1, w1, false, false);
      union { unsigned u[4]; f16x8 v; } pu;
      pu.u[0] = X[0]; pu.u[1] = Y[0]; pu.u[2] = X[1]; pu.u[3] = Y[1];
      pf0 = pu.v;
    }
    {
      const unsigned k0 = pku(x[8],  x[9]);
      const unsigned k1 = pku(x[10], x[11]);
      const unsigned w0 = pku(x[12], x[13]);
      const unsigned w1 = pku(x[14], x[15]);
      auto X = __builtin_amdgcn_permlane32_swap(k0, w0, false, false);
      auto Y = __builtin_amdgcn_permlane32_swap(k1, w1, false, false);
      union { unsigned u[4]; f16x8 v; } pu;
      pu.u[0] = X[0]; pu.u[1] = Y[0]; pu.u[2] = X[1]; pu.u[3] = Y[1];
      pf1 = pu.v;
    }
    const int cur = (s0h >> 6) & 1;
    __builtin_amdgcn_s_setprio(1);
    #pragma unroll
    for (int sc = 0; sc < 2; ++sc) {
      const f16x8 pf = (sc == 0) ? pf0 : pf1;
      const int scg = hf*2 + sc;
      {
        const int sl0 = ((scg << 2) + (hi << 1)) ^ keyv0;
        union { f16x4 h4[2]; f16x8 v; } vu;
        vu.h4[0] = *reinterpret_cast<const f16x4*>(&Vt[cur][vrowb0 + (sl0 << 2)]);
        vu.h4[1] = *reinterpret_cast<const f16x4*>(&Vt[cur][vrowb0 + ((sl0 ^ 1) << 2)]);
        a0 = __builtin_amdgcn_mfma_f32_32x32x16_f16(vu.v, pf, a0, 0, 0, 0);
      }
      {
        const int sl1 = ((scg << 2) + (hi << 1)) ^ keyv1;
        union { f16x4 h4[2]; f16x8 v; } vu;
        vu.h4[0] = *reinterpret_cast<const f16x4*>(&Vt[cur][vrowb1 + (sl1 << 2)]);
        vu.h4[1] = *reinterpret_cast<const f16x4*>(&Vt[cur][vrowb1 + ((sl1 ^ 1) << 2)]);
        a1 = __builtin_amdgcn_mfma_f32_32x32x16_f16(vu.v, pf, a1, 0, 0, 0);
      }
    }
    __builtin_amdgcn_s_setprio(0);
  };

  // ---- prologue: chunk 0 staged, chunk 1 in flight ----
  load_kv(0);
  kv_write(0);
  load_kv(KVB);

  #pragma unroll 2
  for (int c = 0; c < NCH; ++c) {
    const int cur = c & 1;
    const int s0 = c * KVB;
    __syncthreads();
    if (c + 1 < NCH) kv_write(cur ^ 1);        // chunk c+1 (loaded body c-1)
    if (c + 2 < NCH) load_kv((c + 2) * KVB);   // written top of body c+1

    // ---- QK^T for both independent halves ----
    f32x16 ccA = z16, ccB = z16;
    __builtin_amdgcn_s_setprio(1);
    #pragma unroll
    for (int ec = 0; ec < 4; ++ec) {
      const f16x8 kfA = *reinterpret_cast<const f16x8*>(
          &Ks[cur][l31*64 + ((((ec << 2) + (hi << 1)) ^ kxor) << 2)]);
      ccA = __builtin_amdgcn_mfma_f32_32x32x16_f16(kfA, qf[ec], ccA, 0, 0, 0);
    }
    #pragma unroll
    for (int ec = 0; ec < 4; ++ec) {
      const f16x8 kfB = *reinterpret_cast<const f16x8*>(
          &Ks[cur][l31*64 + 2048 + ((((ec << 2) + (hi << 1)) ^ kxor) << 2)]);
      ccB = __builtin_amdgcn_mfma_f32_32x32x16_f16(kfB, qf[ec], ccB, 0, 0, 0);
    }
    __builtin_amdgcn_s_setprio(0);

    // ---- two independent SM->pack->PV chains (scheduler interleaves) ----
    half_tail(ccA, 0, s0,      mA, lA, aA0, aA1);
    half_tail(ccB, 1, s0 + 32, mB, lB, aB0, aB1);
  }

  // ---- epilogue: in-register flash-merge of the two halves, store ----
  lA = xsum32(lA);
  lB = xsum32(lB);
  const float mM = fmaxf(mA, mB);
  const float wA = __builtin_amdgcn_exp2f(mA - mM);
  const float wB = __builtin_amdgcn_exp2f(mB - mM);
  const float inv = 1.f / (lA * wA + lB * wB);
  float* Op = O + (((size_t)n * kL + qrow) * kH + h) * kD;
  #pragma unroll
  for (int m = 0; m < 4; ++m) {
    f32x4 o;
    #pragma unroll
    for (int r = 0; r < 4; ++r)
      o[r] = (aA0[4*m+r] * wA + aB0[4*m+r] * wB) * inv;
    *reinterpret_cast<f32x4*>(Op + 8*m + 4*hi) = o;
  }
  #pragma unroll
  for (int m = 0; m < 4; ++m) {
    f32x4 o;
    #pragma unroll
    for (int r = 0; r < 4; ++r)
      o[r] = (aA1[4*m+r] * wA + aB1[4*m+r] * wB) * inv;
    *reinterpret_cast<f32x4*>(Op + 32 + 8*m + 4*hi) = o;
  }
}

extern "C" void kernel_launch(void* const* d_in, const int* in_sizes, int n_in,
                              void* d_out, int out_size, void* d_ws, size_t ws_size,
                              hipStream_t stream) {
  const float* Q   = (const float*)d_in[0];
  const float* K   = (const float*)d_in[1];
  const float* V   = (const float*)d_in[2];
  const float* M   = (const float*)d_in[3];
  const float* KLN = (const float*)d_in[4];
  float* O = (float*)d_out;

  unsigned* F = nullptr;
  if (ws_size >= sizeof(unsigned)) {
    F = (unsigned*)d_ws;
    hipMemsetAsync(F, 0, sizeof(unsigned), stream);
    flag_kernel<<<dim3(1024), dim3(256), 0, stream>>>(M, KLN, F);
  }

  dim3 grid(kN * kH * (kL / 256));  // 256 blocks (256 q-rows each)
  dim3 block(512);                  // 8 waves, 32 queries each
  attn_fwd_kernel<<<grid, block, 0, stream>>>(Q, K, V, M, KLN, O, F);
}

// Round 25
// 45.891 us; speedup vs baseline: 1.3338x; 1.0009x over previous
//
#include <hip/hip_runtime.h>

typedef _Float16 f16x8  __attribute__((ext_vector_type(8)));
typedef _Float16 f16x4  __attribute__((ext_vector_type(4)));
typedef __fp16   hf2    __attribute__((ext_vector_type(2)));
typedef float    f32x4  __attribute__((ext_vector_type(4)));
typedef float    f32x16 __attribute__((ext_vector_type(16)));

namespace {
constexpr int kN = 4, kL = 1024, kS = 1024, kH = 16, kE = 64, kD = 64;
constexpr int kRowF = kH * kE;     // 1024 floats: s-row stride of K and V
constexpr int KVB = 64;            // keys per LDS chunk
constexpr int NCH = kS / KVB;      // 16 chunks
constexpr float SCL = 0.125f * 1.44269504088896340736f;  // 1/sqrt(E)*log2(e)
}

__device__ __forceinline__ unsigned pku(float a, float b) {
  union { hf2 h; unsigned u; } u;
  u.h = __builtin_amdgcn_cvt_pkrtz(a, b);
  return u.u;
}
__device__ __forceinline__ f16x4 pk4(float a, float b, float c, float d) {
  union { hf2 h2[2]; f16x4 v; } u;
  u.h2[0] = __builtin_amdgcn_cvt_pkrtz(a, b);
  u.h2[1] = __builtin_amdgcn_cvt_pkrtz(c, d);
  return u.v;
}
// cross-half-wave (lane ^32) max/sum via permlane32_swap (pure VALU)
__device__ __forceinline__ float xmax32(float t) {
  union { float f; unsigned u; } tu; tu.f = t;
  auto P = __builtin_amdgcn_permlane32_swap(tu.u, tu.u, false, false);
  union { unsigned u; float f; } a, b; a.u = P[0]; b.u = P[1];
  return fmaxf(a.f, b.f);
}
__device__ __forceinline__ float xsum32(float t) {
  union { float f; unsigned u; } tu; tu.f = t;
  auto P = __builtin_amdgcn_permlane32_swap(tu.u, tu.u, false, false);
  union { unsigned u; float f; } a, b; a.u = P[0]; b.u = P[1];
  return a.f + b.f;
}

// Detect all-zero mask/key_lengths: F[0] stays 0 iff every element is zero.
__global__ __launch_bounds__(256)
void flag_kernel(const float* __restrict__ M, const float* __restrict__ KLN,
                 unsigned* __restrict__ F)
{
  constexpr size_t nM = (size_t)kL * kS / 4, nK = (size_t)kN * kS / 4;
  unsigned any = 0;
  for (size_t i = (size_t)blockIdx.x * 256 + threadIdx.x; i < nM + nK;
       i += (size_t)gridDim.x * 256) {
    const f32x4 v = (i < nM) ? reinterpret_cast<const f32x4*>(M)[i]
                             : reinterpret_cast<const f32x4*>(KLN)[i - nM];
    #pragma unroll
    for (int r = 0; r < 4; ++r)
      any |= (__float_as_uint(v[r]) << 1);   // <<1 drops sign: -0 counts as 0
  }
  if (__any(any != 0) && (threadIdx.x & 63) == 0) atomicOr(F, 1u);
}

// SESSION-BEST structure (R16/R23/R24: 46.8 -> 45.9us) + unroll-4 main loop:
// per unrolled copy, `cur` AND the chunk bases (c*KVB) are compile-time
// constants -> LDS buffer bases fold into immediate offsets and global
// staging addresses strength-reduce across 4 bodies.
// Structure: 8-wave/512-thread block = 256 q of one (n,h); one staged K/V
// chunk serves all 8 waves; role-split reg staging (waves 0-3 K, 4-7 V);
// per-wave half-decoupled chains: the two 32-key halves of each chunk carry
// INDEPENDENT (m,lsum,acc) online-softmax states, flash-merged in registers
// at the epilogue. 32x32x16 MFMA; swapped scores S^T = K.Q^T (C/D
// col=lane&31=q, row=(reg&3)+8*(reg>>2)+4*(lane>>5)=s); XOR-swizzled
// conflict-free LDS; T12 cvt_pkrtz+permlane32_swap P-pack; defer-max THR=8;
// 2-deep prefetch; one __syncthreads per chunk; mask-skip flag.
// CRITICAL (R13-R22): accumulators are NAMED f32x16 values passed as
// individual references (rule #20: address-taken ext_vector arrays go to
// scratch); launch_bounds(512,1) (any bound implying >=4 waves/EU pins
// VGPR<=64..128 and forces scratch spill).
__global__ __launch_bounds__(512, 1)
void attn_fwd_kernel(const float* __restrict__ Q, const float* __restrict__ K,
                     const float* __restrict__ V, const float* __restrict__ M,
                     const float* __restrict__ KLN, float* __restrict__ O,
                     const unsigned* __restrict__ F)
{
  __shared__ _Float16 Ks[2][KVB * 64];
  __shared__ _Float16 Vt[2][kD * 64];

  const int tid  = threadIdx.x;
  const int lane = tid & 63;
  const int wave = tid >> 6;      // 0..7
  const int l31  = lane & 31;     // q within wave-tile; also s/d row in frags
  const int hi   = lane >> 5;
  const bool kRole = (wave < 4);  // staging role (wave-uniform)
  const int srow = (tid >> 4) & 15;
  const int scol = tid & 15;

  const int useMask = F ? (int)F[0] : 1;   // uniform

  // XCD swizzle (256 % 8 == 0 -> bijective)
  const int swz = ((blockIdx.x & 7) << 5) | (blockIdx.x >> 3);
  const int nh = swz >> 2, qb = swz & 3;
  const int h = nh & (kH - 1), n = nh >> 4;
  const int qrow = qb * 256 + wave * 32 + l31;

  const float* Kp = K + ((size_t)n * kS * kH + h) * kE;
  const float* Vp = V + ((size_t)n * kS * kH + h) * kD;
  const float* Lp = KLN + (size_t)n * kS;
  const float* Mp = M + (size_t)qrow * kS;

  // ---- hoisted Q B-frags (pre-scaled): qf[ec], k = 16*ec + 8*hi + j ----
  f16x8 qf[4];
  {
    const float* Qp = Q + ((size_t)((size_t)n * kL + qrow) * kH + h) * kE;
    #pragma unroll
    for (int ec = 0; ec < 4; ++ec) {
      const f32x4 a = *reinterpret_cast<const f32x4*>(Qp + 16*ec + 8*hi);
      const f32x4 b = *reinterpret_cast<const f32x4*>(Qp + 16*ec + 8*hi + 4);
      union { f16x4 h4[2]; f16x8 v; } u;
      u.h4[0] = pk4(a[0]*SCL, a[1]*SCL, a[2]*SCL, a[3]*SCL);
      u.h4[1] = pk4(b[0]*SCL, b[1]*SCL, b[2]*SCL, b[3]*SCL);
      qf[ec] = u.v;
    }
  }

  // ---- per-thread LDS constants (named scalars; verified round-6 math) ----
  const int kxor = (l31 & 7) << 1;
  const int d0 = l31,      d1 = 32 + l31;
  const int keyv0 = ((4*((d0>>2)&3) + (d0&3)) ^ (d0>>2)) & 15;
  const int keyv1 = ((4*((d1>>2)&3) + (d1&3)) ^ (d1>>2)) & 15;
  const int vrowb0 = d0 * 64, vrowb1 = d1 * 64;
  int hwv[4];
  #pragma unroll
  for (int jd = 0; jd < 4; ++jd)
    hwv[jd] = ((4*(scol & 3) + jd) ^ scol) & 15;

  const f32x16 z16 = {0,0,0,0, 0,0,0,0, 0,0,0,0, 0,0,0,0};
  f32x16 aA0 = z16, aA1 = z16, aB0 = z16, aB1 = z16;   // named accumulators
  float mA = -1e30f, lA = 0.f, mB = -1e30f, lB = 0.f;

  // ---- role-split staging: K waves load 4 K-rows, V waves one V quad ----
  f32x4 sg[4];
  auto load_kv = [&](int sbase) {
    if (kRole) {
      #pragma unroll
      for (int i = 0; i < 4; ++i)
        sg[i] = *reinterpret_cast<const f32x4*>(Kp + (size_t)(sbase + 16*i + srow) * kRowF + 4*scol);
    } else {
      #pragma unroll
      for (int js = 0; js < 4; ++js)
        sg[js] = *reinterpret_cast<const f32x4*>(Vp + (size_t)(sbase + 4*srow + js) * kRowF + 4*scol);
    }
  };
  auto kv_write = [&](int buf) {
    if (kRole) {
      #pragma unroll
      for (int i = 0; i < 4; ++i) {
        const int s = 16*i + srow;
        *reinterpret_cast<f16x4*>(&Ks[buf][s*64 + ((scol ^ ((s & 7) << 1)) << 2)]) =
            pk4(sg[i][0], sg[i][1], sg[i][2], sg[i][3]);
      }
    } else {
      #pragma unroll
      for (int jd = 0; jd < 4; ++jd) {
        const int d = 4*scol + jd;
        *reinterpret_cast<f16x4*>(&Vt[buf][d*64 + ((srow ^ hwv[jd]) << 2)]) =
            pk4(sg[0][jd], sg[1][jd], sg[2][jd], sg[3][jd]);
      }
    }
  };

  // one 32-key half: logits -> per-half online softmax -> pack -> PV.
  // Accumulators passed as INDIVIDUAL references (never address-taken).
  auto half_tail = [&](const f32x16& cc, int hf, int s0h, float& mrun,
                       float& lsum, f32x16& a0, f32x16& a1) {
    float x[16];
    if (useMask) {
      #pragma unroll
      for (int m = 0; m < 4; ++m) {
        const f32x4 mv = *reinterpret_cast<const f32x4*>(Mp + s0h + 8*m + 4*hi);
        const f32x4 lv = *reinterpret_cast<const f32x4*>(Lp + s0h + 8*m + 4*hi);
        #pragma unroll
        for (int r = 0; r < 4; ++r)
          x[4*m+r] = fmaf(mv[r] + lv[r], SCL, cc[4*m+r]);
      }
    } else {
      #pragma unroll
      for (int r = 0; r < 16; ++r) x[r] = cc[r];
    }
    float mx[8];
    #pragma unroll
    for (int i = 0; i < 8; ++i) mx[i] = fmaxf(x[i], x[i+8]);
    #pragma unroll
    for (int w = 4; w >= 1; w >>= 1)
      #pragma unroll
      for (int i = 0; i < w; ++i) mx[i] = fmaxf(mx[i], mx[i+w]);
    const float tmax = xmax32(mx[0]);

    if (!__all(tmax <= mrun + 8.f)) {        // defer-max THR=8 (log2)
      const float mnew = fmaxf(mrun, tmax);
      const float rs = __builtin_amdgcn_exp2f(mrun - mnew);
      mrun = mnew; lsum *= rs;
      a0 *= rs; a1 *= rs;
    }
    #pragma unroll
    for (int i = 0; i < 16; ++i)
      x[i] = __builtin_amdgcn_exp2f(x[i] - mrun);
    float s8[8];
    #pragma unroll
    for (int i = 0; i < 8; ++i) s8[i] = x[i] + x[i+8];
    #pragma unroll
    for (int w = 4; w >= 1; w >>= 1)
      #pragma unroll
      for (int i = 0; i < w; ++i) s8[i] += s8[i+w];
    lsum += s8[0];

    // pack P -> 2 PV B-frags via cvt_pk + permlane32_swap (verified)
    f16x8 pf0, pf1;
    {
      const unsigned k0 = pku(x[0], x[1]);
      const unsigned k1 = pku(x[2], x[3]);
      const unsigned w0 = pku(x[4], x[5]);
      const unsigned w1 = pku(x[6], x[7]);
      auto X = __builtin_amdgcn_permlane32_swap(k0, w0, false, false);
      auto Y = __builtin_amdgcn_permlane32_swap(k1, w1, false, false);
      union { unsigned u[4]; f16x8 v; } pu;
      pu.u[0] = X[0]; pu.u[1] = Y[0]; pu.u[2] = X[1]; pu.u[3] = Y[1];
      pf0 = pu.v;
    }
    {
      const unsigned k0 = pku(x[8],  x[9]);
      const unsigned k1 = pku(x[10], x[11]);
      const unsigned w0 = pku(x[12], x[13]);
      const unsigned w1 = pku(x[14], x[15]);
      auto X = __builtin_amdgcn_permlane32_swap(k0, w0, false, false);
      auto Y = __builtin_amdgcn_permlane32_swap(k1, w1, false, false);
      union { unsigned u[4]; f16x8 v; } pu;
      pu.u[0] = X[0]; pu.u[1] = Y[0]; pu.u[2] = X[1]; pu.u[3] = Y[1];
      pf1 = pu.v;
    }
    const int cur = (s0h >> 6) & 1;
    __builtin_amdgcn_s_setprio(1);
    #pragma unroll
    for (int sc = 0; sc < 2; ++sc) {
      const f16x8 pf = (sc == 0) ? pf0 : pf1;
      const int scg = hf*2 + sc;
      {
        const int sl0 = ((scg << 2) + (hi << 1)) ^ keyv0;
        union { f16x4 h4[2]; f16x8 v; } vu;
        vu.h4[0] = *reinterpret_cast<const f16x4*>(&Vt[cur][vrowb0 + (sl0 << 2)]);
        vu.h4[1] = *reinterpret_cast<const f16x4*>(&Vt[cur][vrowb0 + ((sl0 ^ 1) << 2)]);
        a0 = __builtin_amdgcn_mfma_f32_32x32x16_f16(vu.v, pf, a0, 0, 0, 0);
      }
      {
        const int sl1 = ((scg << 2) + (hi << 1)) ^ keyv1;
        union { f16x4 h4[2]; f16x8 v; } vu;
        vu.h4[0] = *reinterpret_cast<const f16x4*>(&Vt[cur][vrowb1 + (sl1 << 2)]);
        vu.h4[1] = *reinterpret_cast<const f16x4*>(&Vt[cur][vrowb1 + ((sl1 ^ 1) << 2)]);
        a1 = __builtin_amdgcn_mfma_f32_32x32x16_f16(vu.v, pf, a1, 0, 0, 0);
      }
    }
    __builtin_amdgcn_s_setprio(0);
  };

  // ---- prologue: chunk 0 staged, chunk 1 in flight ----
  load_kv(0);
  kv_write(0);
  load_kv(KVB);

  #pragma unroll 4
  for (int c = 0; c < NCH; ++c) {
    const int cur = c & 1;
    const int s0 = c * KVB;
    __syncthreads();
    if (c + 1 < NCH) kv_write(cur ^ 1);        // chunk c+1 (loaded body c-1)
    if (c + 2 < NCH) load_kv((c + 2) * KVB);   // written top of body c+1

    // ---- QK^T for both independent halves ----
    f32x16 ccA = z16, ccB = z16;
    __builtin_amdgcn_s_setprio(1);
    #pragma unroll
    for (int ec = 0; ec < 4; ++ec) {
      const f16x8 kfA = *reinterpret_cast<const f16x8*>(
          &Ks[cur][l31*64 + ((((ec << 2) + (hi << 1)) ^ kxor) << 2)]);
      ccA = __builtin_amdgcn_mfma_f32_32x32x16_f16(kfA, qf[ec], ccA, 0, 0, 0);
    }
    #pragma unroll
    for (int ec = 0; ec < 4; ++ec) {
      const f16x8 kfB = *reinterpret_cast<const f16x8*>(
          &Ks[cur][l31*64 + 2048 + ((((ec << 2) + (hi << 1)) ^ kxor) << 2)]);
      ccB = __builtin_amdgcn_mfma_f32_32x32x16_f16(kfB, qf[ec], ccB, 0, 0, 0);
    }
    __builtin_amdgcn_s_setprio(0);

    // ---- two independent SM->pack->PV chains (scheduler interleaves) ----
    half_tail(ccA, 0, s0,      mA, lA, aA0, aA1);
    half_tail(ccB, 1, s0 + 32, mB, lB, aB0, aB1);
  }

  // ---- epilogue: in-register flash-merge of the two halves, store ----
  lA = xsum32(lA);
  lB = xsum32(lB);
  const float mM = fmaxf(mA, mB);
  const float wA = __builtin_amdgcn_exp2f(mA - mM);
  const float wB = __builtin_amdgcn_exp2f(mB - mM);
  const float inv = 1.f / (lA * wA + lB * wB);
  float* Op = O + (((size_t)n * kL + qrow) * kH + h) * kD;
  #pragma unroll
  for (int m = 0; m < 4; ++m) {
    f32x4 o;
    #pragma unroll
    for (int r = 0; r < 4; ++r)
      o[r] = (aA0[4*m+r] * wA + aB0[4*m+r] * wB) * inv;
    *reinterpret_cast<f32x4*>(Op + 8*m + 4*hi) = o;
  }
  #pragma unroll
  for (int m = 0; m < 4; ++m) {
    f32x4 o;
    #pragma unroll
    for (int r = 0; r < 4; ++r)
      o[r] = (aA1[4*m+r] * wA + aB1[4*m+r] * wB) * inv;
    *reinterpret_cast<f32x4*>(Op + 32 + 8*m + 4*hi) = o;
  }
}

extern "C" void kernel_launch(void* const* d_in, const int* in_sizes, int n_in,
                              void* d_out, int out_size, void* d_ws, size_t ws_size,
                              hipStream_t stream) {
  const float* Q   = (const float*)d_in[0];
  const float* K   = (const float*)d_in[1];
  const float* V   = (const float*)d_in[2];
  const float* M   = (const float*)d_in[3];
  const float* KLN = (const float*)d_in[4];
  float* O = (float*)d_out;

  unsigned* F = nullptr;
  if (ws_size >= sizeof(unsigned)) {
    F = (unsigned*)d_ws;
    hipMemsetAsync(F, 0, sizeof(unsigned), stream);
    flag_kernel<<<dim3(1024), dim3(256), 0, stream>>>(M, KLN, F);
  }

  dim3 grid(kN * kH * (kL / 256));  // 256 blocks (256 q-rows each)
  dim3 block(512);                  // 8 waves, 32 queries each
  attn_fwd_kernel<<<grid, block, 0, stream>>>(Q, K, V, M, KLN, O, F);
}